// Round 1
// baseline (385.549 us; speedup 1.0000x reference)
//
#include <hip/hip_runtime.h>
#include <math.h>

#define DD 256
#define SS 64
#define BT 2048
#define TT 16

__global__ void k_bn(const float* __restrict__ Hs, const float* __restrict__ g,
                     const float* __restrict__ b, float* __restrict__ hs) {
    int j = threadIdx.x;
    float sum = 0.f, sumsq = 0.f;
    for (int s = 0; s < SS; ++s) {
        float v = Hs[s * DD + j];
        sum += v; sumsq += v * v;
    }
    float mu  = sum * (1.f / SS);
    float var = sumsq * (1.f / SS) - mu * mu;   // biased, matches jnp.var / torch BN
    float sc  = rsqrtf(var + 1e-5f) * g[j];
    float sh  = b[j] - mu * sc;
    for (int s = 0; s < SS; ++s)
        hs[s * DD + j] = Hs[s * DD + j] * sc + sh;
}

// out[s][j] = act( sum_d in[s][d] * W[d][j] + bias[j] )   grid=(64), block=(256)
template <bool RELU>
__global__ void k_slotfc(const float* __restrict__ in, const float* __restrict__ W,
                         const float* __restrict__ bias, float* __restrict__ out) {
    __shared__ float row[DD];
    int s = blockIdx.x, j = threadIdx.x;
    row[j] = in[s * DD + j];
    __syncthreads();
    float acc = bias[j];
#pragma unroll 4
    for (int d = 0; d < DD; ++d)
        acc = fmaf(row[d], W[d * DD + j], acc);
    if (RELU) acc = fmaxf(acc, 0.f);
    out[s * DD + j] = acc;
}

// X1 = Hx @ W1a   grid=(128), block=(256), 16 tokens per block
__global__ void k_x1(const float* __restrict__ Hx, const float* __restrict__ W,
                     float* __restrict__ X1) {
    __shared__ float xt[TT][DD];
    int t0 = blockIdx.x * TT, j = threadIdx.x;
    for (int tt = 0; tt < TT; ++tt)
        xt[tt][j] = Hx[(t0 + tt) * DD + j];
    __syncthreads();
    float acc[TT] = {};
    for (int d4 = 0; d4 < DD / 4; ++d4) {
        float c0 = W[(4 * d4 + 0) * DD + j];
        float c1 = W[(4 * d4 + 1) * DD + j];
        float c2 = W[(4 * d4 + 2) * DD + j];
        float c3 = W[(4 * d4 + 3) * DD + j];
#pragma unroll
        for (int tt = 0; tt < TT; ++tt) {
            const float4 x4 = *reinterpret_cast<const float4*>(&xt[tt][4 * d4]);
            acc[tt] = fmaf(x4.x, c0, fmaf(x4.y, c1, fmaf(x4.z, c2, fmaf(x4.w, c3, acc[tt]))));
        }
    }
    for (int tt = 0; tt < TT; ++tt)
        X1[(t0 + tt) * DD + j] = acc[tt];
}

// atten[t][s] = w2 . relu(X1[t]+S1b[s]+ (Hx[t]*m[s])@C ) + b2
// grid=(128,64) block=(256)
__global__ void k_main(const float* __restrict__ Hx, const float* __restrict__ m,
                       const float* __restrict__ C, const float* __restrict__ X1,
                       const float* __restrict__ S1b, const float* __restrict__ w2,
                       const float* __restrict__ w_b2, float* __restrict__ atten) {
    __shared__ float xm[TT][DD];
    __shared__ float red[TT][4];
    int s  = blockIdx.y;
    int t0 = blockIdx.x * TT;
    int j  = threadIdx.x;
    float mj = m[s * DD + j];
    for (int tt = 0; tt < TT; ++tt)
        xm[tt][j] = Hx[(t0 + tt) * DD + j] * mj;
    __syncthreads();
    float acc[TT] = {};
    for (int d4 = 0; d4 < DD / 4; ++d4) {
        float c0 = C[(4 * d4 + 0) * DD + j];
        float c1 = C[(4 * d4 + 1) * DD + j];
        float c2 = C[(4 * d4 + 2) * DD + j];
        float c3 = C[(4 * d4 + 3) * DD + j];
#pragma unroll
        for (int tt = 0; tt < TT; ++tt) {
            const float4 x4 = *reinterpret_cast<const float4*>(&xm[tt][4 * d4]);
            acc[tt] = fmaf(x4.x, c0, fmaf(x4.y, c1, fmaf(x4.z, c2, fmaf(x4.w, c3, acc[tt]))));
        }
    }
    float s1  = S1b[s * DD + j];
    float w2j = w2[j];
    int lane = j & 63, w = j >> 6;
#pragma unroll
    for (int tt = 0; tt < TT; ++tt) {
        float h = fmaxf(acc[tt] + X1[(t0 + tt) * DD + j] + s1, 0.f);
        float c = h * w2j;
#pragma unroll
        for (int off = 32; off; off >>= 1) c += __shfl_down(c, off);
        if (lane == 0) red[tt][w] = c;
    }
    __syncthreads();
    if (j < TT) {
        float r = red[j][0] + red[j][1] + red[j][2] + red[j][3];
        atten[(t0 + j) * SS + s] = r + w_b2[0];
    }
}

// softmax over slots + G = score@transHs + output assembly. one wave per token.
// grid=(512) block=(256)
__global__ void k_out(const float* __restrict__ Hx, const float* __restrict__ m,
                      const float* __restrict__ atten, float* __restrict__ outU,
                      float* __restrict__ outA) {
    int wave = threadIdx.x >> 6, lane = threadIdx.x & 63;
    int t = blockIdx.x * 4 + wave;
    float a = atten[t * SS + lane];
    float mx = a;
#pragma unroll
    for (int off = 32; off; off >>= 1) mx = fmaxf(mx, __shfl_xor(mx, off));
    float e = __expf(a - mx);
    float sum = e;
#pragma unroll
    for (int off = 32; off; off >>= 1) sum += __shfl_xor(sum, off);
    float p = e / sum;
    outA[t * SS + lane] = p;
    float gacc[4] = {};
    for (int s = 0; s < SS; ++s) {
        float ps = __shfl(p, s);
#pragma unroll
        for (int q = 0; q < 4; ++q)
            gacc[q] = fmaf(ps, m[s * DD + lane + 64 * q], gacc[q]);
    }
#pragma unroll
    for (int q = 0; q < 4; ++q) {
        int j = lane + 64 * q;
        float x = Hx[t * DD + j];
        outU[t * 2 * DD + j] = x;
        outU[t * 2 * DD + DD + j] = x + gacc[q];
    }
}

extern "C" void kernel_launch(void* const* d_in, const int* in_sizes, int n_in,
                              void* d_out, int out_size, void* d_ws, size_t ws_size,
                              hipStream_t stream) {
    const float* Hx   = (const float*)d_in[0];
    const float* Hs   = (const float*)d_in[1];
    const float* bn_g = (const float*)d_in[2];
    const float* bn_b = (const float*)d_in[3];
    const float* s_w1 = (const float*)d_in[4];
    const float* s_b1 = (const float*)d_in[5];
    const float* s_w2 = (const float*)d_in[6];
    const float* s_b2 = (const float*)d_in[7];
    const float* w_w1 = (const float*)d_in[8];
    const float* w_b1 = (const float*)d_in[9];
    const float* w_w2 = (const float*)d_in[10];
    const float* w_b2 = (const float*)d_in[11];

    float* ws      = (float*)d_ws;
    float* hs      = ws;                    // 64*256
    float* t1      = ws + 16384;            // 64*256
    float* transHs = ws + 32768;            // 64*256
    float* S1b     = ws + 49152;            // 64*256
    float* X1      = ws + 65536;            // 2048*256
    float* atten   = ws + 65536 + 524288;   // 2048*64   (total 2.88 MB)

    float* outU = (float*)d_out;            // [2048][512]
    float* outA = outU + BT * 2 * DD;       // [2048][64]

    k_bn<<<1, 256, 0, stream>>>(Hs, bn_g, bn_b, hs);
    k_slotfc<true ><<<SS, 256, 0, stream>>>(hs, s_w1, s_b1, t1);
    k_slotfc<false><<<SS, 256, 0, stream>>>(t1, s_w2, s_b2, transHs);
    // S1b = transHs @ w_w1[256:512] + w_b1
    k_slotfc<false><<<SS, 256, 0, stream>>>(transHs, w_w1 + 256 * DD, w_b1, S1b);
    k_x1<<<BT / TT, 256, 0, stream>>>(Hx, w_w1, X1);
    dim3 gmain(BT / TT, SS);
    k_main<<<gmain, 256, 0, stream>>>(Hx, transHs, w_w1 + 512 * DD, X1, S1b,
                                      w_w2, w_b2, atten);
    k_out<<<BT / 4, 256, 0, stream>>>(Hx, transHs, atten, outU, outA);
}

// Round 2
// 124.086 us; speedup vs baseline: 3.1071x; 3.1071x over previous
//
#include <hip/hip_runtime.h>
#include <math.h>

#define DD 256
#define SS 64
#define BT 2048
#define TT 16

typedef __attribute__((ext_vector_type(4))) float f32x4;
typedef __attribute__((ext_vector_type(8))) short bf16x8;
typedef __attribute__((ext_vector_type(4))) unsigned int u32x4;

__device__ inline unsigned pack_bf16(float a, float b) {
    unsigned ua = __builtin_bit_cast(unsigned, a);
    unsigned ub = __builtin_bit_cast(unsigned, b);
    ua = (ua + 0x7fffu + ((ua >> 16) & 1u)) >> 16;
    ub = (ub + 0x7fffu + ((ub >> 16) & 1u)) >> 16;
    return ua | (ub << 16);
}

__global__ void k_bn(const float* __restrict__ Hs, const float* __restrict__ g,
                     const float* __restrict__ b, float* __restrict__ hs) {
    int j = threadIdx.x;
    float sum = 0.f, sumsq = 0.f;
    for (int s = 0; s < SS; ++s) {
        float v = Hs[s * DD + j];
        sum += v; sumsq += v * v;
    }
    float mu  = sum * (1.f / SS);
    float var = sumsq * (1.f / SS) - mu * mu;
    float sc  = rsqrtf(var + 1e-5f) * g[j];
    float sh  = b[j] - mu * sc;
    for (int s = 0; s < SS; ++s)
        hs[s * DD + j] = Hs[s * DD + j] * sc + sh;
}

template <bool RELU>
__global__ void k_slotfc(const float* __restrict__ in, const float* __restrict__ W,
                         const float* __restrict__ bias, float* __restrict__ out) {
    __shared__ float row[DD];
    int s = blockIdx.x, j = threadIdx.x;
    row[j] = in[s * DD + j];
    __syncthreads();
    float acc = bias[j];
#pragma unroll 4
    for (int d = 0; d < DD; ++d)
        acc = fmaf(row[d], W[d * DD + j], acc);
    if (RELU) acc = fmaxf(acc, 0.f);
    out[s * DD + j] = acc;
}

__global__ void k_x1(const float* __restrict__ Hx, const float* __restrict__ W,
                     float* __restrict__ X1) {
    __shared__ float xt[TT][DD];
    int t0 = blockIdx.x * TT, j = threadIdx.x;
    for (int tt = 0; tt < TT; ++tt)
        xt[tt][j] = Hx[(t0 + tt) * DD + j];
    __syncthreads();
    float acc[TT] = {};
    for (int d4 = 0; d4 < DD / 4; ++d4) {
        float c0 = W[(4 * d4 + 0) * DD + j];
        float c1 = W[(4 * d4 + 1) * DD + j];
        float c2 = W[(4 * d4 + 2) * DD + j];
        float c3 = W[(4 * d4 + 3) * DD + j];
#pragma unroll
        for (int tt = 0; tt < TT; ++tt) {
            const float4 x4 = *reinterpret_cast<const float4*>(&xt[tt][4 * d4]);
            acc[tt] = fmaf(x4.x, c0, fmaf(x4.y, c1, fmaf(x4.z, c2, fmaf(x4.w, c3, acc[tt]))));
        }
    }
    for (int tt = 0; tt < TT; ++tt)
        X1[(t0 + tt) * DD + j] = acc[tt];
}

// Pack C (= w_w1 rows 512..767) into MFMA B-fragment order:
// Bpack[((nt*8+ks)*64+lane)*4 + e2] u32 = bf16x2 of C[k][j],
//   j = nt*16 + (lane&15),  k = ks*32 + (lane>>4)*8 + 2*e2 + {0,1}
__global__ void k_pack(const float* __restrict__ C, unsigned* __restrict__ Bpack) {
    int idx = blockIdx.x * 256 + threadIdx.x;  // 0..8191
    int lane = idx & 63;
    int ks = (idx >> 6) & 7;
    int nt = idx >> 9;
    int j = nt * 16 + (lane & 15);
    int k0 = ks * 32 + (lane >> 4) * 8;
    unsigned out[4];
#pragma unroll
    for (int e = 0; e < 4; ++e) {
        float f0 = C[(k0 + 2 * e) * DD + j];
        float f1 = C[(k0 + 2 * e + 1) * DD + j];
        out[e] = pack_bf16(f0, f1);
    }
    *(u32x4*)(Bpack + idx * 4) = *(const u32x4*)out;
}

// atten[t][s] = w2 . relu( (Hx[t]*m[s])@C + X1[t] + S1b[s] ) + b2
// grid=(32, 64) block=256 (4 waves). 64 tokens x 256 j per block via MFMA.
__global__ __launch_bounds__(256) void
k_main_mfma(const float* __restrict__ Hx, const float* __restrict__ m,
            const unsigned* __restrict__ Bpack, const float* __restrict__ X1,
            const float* __restrict__ S1b, const float* __restrict__ w2,
            const float* __restrict__ w_b2, float* __restrict__ atten) {
    __shared__ unsigned Abuf[64 * 128];  // 64 rows x 512B (bf16, swizzled) = 32 KB
    __shared__ float attp[4][64];
    const int s   = blockIdx.y;
    const int t0  = blockIdx.x * 64;
    const int tid = threadIdx.x;

    // ---- stage A = bf16(Hx[t0+r] * m[s]) into LDS (XOR-swizzled rows)
    {
        const int r    = tid >> 2;          // 0..63
        const int kseg = (tid & 3) * 64;    // 64 k's per thread
        const float* xrow = Hx + (t0 + r) * DD + kseg;
        const float* mrow = m + s * DD + kseg;
#pragma unroll
        for (int c = 0; c < 8; ++c) {       // 8 k per 16B chunk
            float4 x0 = *(const float4*)(xrow + c * 8);
            float4 x1 = *(const float4*)(xrow + c * 8 + 4);
            float4 m0 = *(const float4*)(mrow + c * 8);
            float4 m1 = *(const float4*)(mrow + c * 8 + 4);
            unsigned p[4];
            p[0] = pack_bf16(x0.x * m0.x, x0.y * m0.y);
            p[1] = pack_bf16(x0.z * m0.z, x0.w * m0.w);
            p[2] = pack_bf16(x1.x * m1.x, x1.y * m1.y);
            p[3] = pack_bf16(x1.z * m1.z, x1.w * m1.w);
            int kbyte = (kseg + c * 8) * 2;
            int byte  = r * 512 + (kbyte ^ ((r & 7) << 4));
            *(u32x4*)((char*)Abuf + byte) = *(const u32x4*)p;
        }
    }
    __syncthreads();

    const int w    = tid >> 6;
    const int l    = tid & 63;
    const int lrow = l & 15;   // A row within M-tile / B col within N-tile
    const int lg   = l >> 4;   // k sub-group

    f32x4 acc[4][4] = {};

    for (int ks = 0; ks < 8; ++ks) {
        bf16x8 af[4];
        const int kbyte = ks * 64 + lg * 16;
#pragma unroll
        for (int mt = 0; mt < 4; ++mt) {
            int row  = mt * 16 + lrow;
            int byte = row * 512 + (kbyte ^ ((row & 7) << 4));
            af[mt] = *(const bf16x8*)((const char*)Abuf + byte);
        }
#pragma unroll
        for (int nt = 0; nt < 4; ++nt) {
            const bf16x8 bf = *(const bf16x8*)(Bpack + (((w * 4 + nt) * 8 + ks) * 64 + l) * 4);
#pragma unroll
            for (int mt = 0; mt < 4; ++mt)
                acc[mt][nt] = __builtin_amdgcn_mfma_f32_16x16x32_bf16(af[mt], bf, acc[mt][nt], 0, 0, 0);
        }
    }

    // ---- epilogue: h = relu(acc + X1 + S1b); partial = h . w2 ; reduce
    float s1[4], w2v[4];
#pragma unroll
    for (int nt = 0; nt < 4; ++nt) {
        int jn = (w * 4 + nt) * 16 + lrow;
        s1[nt]  = S1b[s * DD + jn];
        w2v[nt] = w2[jn];
    }
#pragma unroll
    for (int mt = 0; mt < 4; ++mt) {
#pragma unroll
        for (int i = 0; i < 4; ++i) {
            const int t = t0 + mt * 16 + lg * 4 + i;
            float p = 0.f;
#pragma unroll
            for (int nt = 0; nt < 4; ++nt) {
                int jn = (w * 4 + nt) * 16 + lrow;
                float h = acc[mt][nt][i] + X1[t * DD + jn] + s1[nt];
                h = fmaxf(h, 0.f);
                p = fmaf(h, w2v[nt], p);
            }
            p += __shfl_xor(p, 1);
            p += __shfl_xor(p, 2);
            p += __shfl_xor(p, 4);
            p += __shfl_xor(p, 8);
            if (lrow == 0) attp[w][mt * 16 + lg * 4 + i] = p;
        }
    }
    __syncthreads();
    if (tid < 64) {
        float r = attp[0][tid] + attp[1][tid] + attp[2][tid] + attp[3][tid] + w_b2[0];
        atten[(t0 + tid) * SS + s] = r;
    }
}

__global__ void k_out(const float* __restrict__ Hx, const float* __restrict__ m,
                      const float* __restrict__ atten, float* __restrict__ outU,
                      float* __restrict__ outA) {
    int wave = threadIdx.x >> 6, lane = threadIdx.x & 63;
    int t = blockIdx.x * 4 + wave;
    float a = atten[t * SS + lane];
    float mx = a;
#pragma unroll
    for (int off = 32; off; off >>= 1) mx = fmaxf(mx, __shfl_xor(mx, off));
    float e = __expf(a - mx);
    float sum = e;
#pragma unroll
    for (int off = 32; off; off >>= 1) sum += __shfl_xor(sum, off);
    float p = e / sum;
    outA[t * SS + lane] = p;
    float gacc[4] = {};
    for (int s = 0; s < SS; ++s) {
        float ps = __shfl(p, s);
#pragma unroll
        for (int q = 0; q < 4; ++q)
            gacc[q] = fmaf(ps, m[s * DD + lane + 64 * q], gacc[q]);
    }
#pragma unroll
    for (int q = 0; q < 4; ++q) {
        int j = lane + 64 * q;
        float x = Hx[t * DD + j];
        outU[t * 2 * DD + j] = x;
        outU[t * 2 * DD + DD + j] = x + gacc[q];
    }
}

extern "C" void kernel_launch(void* const* d_in, const int* in_sizes, int n_in,
                              void* d_out, int out_size, void* d_ws, size_t ws_size,
                              hipStream_t stream) {
    const float* Hx   = (const float*)d_in[0];
    const float* Hs   = (const float*)d_in[1];
    const float* bn_g = (const float*)d_in[2];
    const float* bn_b = (const float*)d_in[3];
    const float* s_w1 = (const float*)d_in[4];
    const float* s_b1 = (const float*)d_in[5];
    const float* s_w2 = (const float*)d_in[6];
    const float* s_b2 = (const float*)d_in[7];
    const float* w_w1 = (const float*)d_in[8];
    const float* w_b1 = (const float*)d_in[9];
    const float* w_w2 = (const float*)d_in[10];
    const float* w_b2 = (const float*)d_in[11];

    float* ws      = (float*)d_ws;
    float* hs      = ws;                       // 64*256
    float* t1      = ws + 16384;               // 64*256
    float* transHs = ws + 32768;               // 64*256
    float* S1b     = ws + 49152;               // 64*256
    float* X1      = ws + 65536;               // 2048*256
    float* atten   = ws + 65536 + 524288;      // 2048*64
    unsigned* Bpack = (unsigned*)(ws + 65536 + 524288 + 131072);  // 32768 u32 = 128 KB

    float* outU = (float*)d_out;               // [2048][512]
    float* outA = outU + BT * 2 * DD;          // [2048][64]

    k_pack<<<32, 256, 0, stream>>>(w_w1 + 512 * DD, Bpack);
    k_bn<<<1, 256, 0, stream>>>(Hs, bn_g, bn_b, hs);
    k_slotfc<true ><<<SS, 256, 0, stream>>>(hs, s_w1, s_b1, t1);
    k_slotfc<false><<<SS, 256, 0, stream>>>(t1, s_w2, s_b2, transHs);
    k_slotfc<false><<<SS, 256, 0, stream>>>(transHs, w_w1 + 256 * DD, w_b1, S1b);
    k_x1<<<BT / TT, 256, 0, stream>>>(Hx, w_w1, X1);
    dim3 gmain(BT / 64, SS);
    k_main_mfma<<<gmain, 256, 0, stream>>>(Hx, transHs, Bpack, X1, S1b,
                                           w_w2, w_b2, atten);
    k_out<<<BT / 4, 256, 0, stream>>>(Hx, transHs, atten, outU, outA);
}